// Round 4
// baseline (914.006 us; speedup 1.0000x reference)
//
#include <hip/hip_runtime.h>
#include <hip/hip_bf16.h>
#include <string.h>

// GNN layer, round 4: halve the atomic-op wall by projecting messages
// through We2 BEFORE the scatter (reference order!):
//   AB = nf @ [We1_s|We1_d]                      (gemm_ab, unchanged)
//   edge_proj (per 64-edge block, full 256 emb feats):
//     C  = ef_tile @ We1_e        (MFMA, K=64) -> LDS
//     msg = lrelu(A[oth]+B[own]+C) built as MFMA A-frags in registers
//     Y  = msg @ We2              (MFMA, K=256, fp32 accum) -> LDS
//     H[own] += Y                 (pk_add_bf16, 128-dim -> 64M ops vs 128M)
//   mlp:  hid = lrelu([nf|H]@Wn1) ; out = hid @ Wn2   (red phase deleted:
//         H IS red now)
// Evidence: atomic wall = 128M ops/430us = 297.7G/s = ~1 op/clk/slice;
// payload per op is fixed, so halving OPS is the only atomic-side lever.

using f32x4  = __attribute__((ext_vector_type(4))) float;
using bf16x8 = __attribute__((ext_vector_type(8))) short;

#define LROW 72    // ef staging pitch (bf16 units)
#define CSROW 264  // Cs pitch: 64 rows x 256 cols C tile
#define YROW 132   // Ys pitch: 128 rows x 128 cols Y tile (aliases Cs: 16896 each)
#define P128 132   // K=128 LDS tile pitch
#define P256 264   // K=256 LDS tile pitch

__device__ __forceinline__ float lrelu(float x) { return x >= 0.f ? x : 0.01f * x; }

__device__ __forceinline__ ushort f2bf(float f) {
    union { float f; unsigned u; } v; v.f = f;
    unsigned u = v.u;
    return (ushort)((u + 0x7fffu + ((u >> 16) & 1u)) >> 16);   // RNE
}
__device__ __forceinline__ float bf2f(ushort u) {
    union { unsigned u; float f; } v; v.u = ((unsigned)u) << 16; return v.f;
}

__device__ __forceinline__ void atomic_pk_add_bf16(void* addr, unsigned val) {
    asm volatile("global_atomic_pk_add_bf16 %0, %1, off" : : "v"(addr), "v"(val) : "memory");
}

// ---------------- AB GEMM: X staged once, W frags from global (round 3) ----
__global__ __launch_bounds__(256) void gemm_ab(
    const ushort* __restrict__ X,     // [Np,128] bf16
    const ushort* __restrict__ Wt,    // [512,128] bf16
    ushort* __restrict__ out)         // [Np,512] bf16
{
    __shared__ ushort Xs[128 * P128];
    const int tid  = threadIdx.x;
    const int lane = tid & 63;
    const int wv   = tid >> 6;
    const int wm   = wv >> 1, wn = wv & 1;
    const int row0 = blockIdx.x * 128;

    #pragma unroll
    for (int q = 0; q < 8; ++q) {
        int idx = q * 256 + tid;
        int r = idx >> 4, c = idx & 15;
        *reinterpret_cast<uint4*>(&Xs[r * P128 + c * 8]) =
            *reinterpret_cast<const uint4*>(X + (size_t)(row0 + r) * 128 + c * 8);
    }
    __syncthreads();

    const int g8 = (lane >> 4) * 8;
    for (int cb = 0; cb < 4; ++cb) {
        f32x4 acc[4][4] = {};
        #pragma unroll
        for (int ks = 0; ks < 4; ++ks) {
            bf16x8 af[4], bf[4];
            #pragma unroll
            for (int i = 0; i < 4; ++i) {
                int mrow = wm * 64 + i * 16 + (lane & 15);
                af[i] = *reinterpret_cast<const bf16x8*>(&Xs[mrow * P128 + ks * 32 + g8]);
                int nc = cb * 128 + wn * 64 + i * 16 + (lane & 15);
                bf[i] = *reinterpret_cast<const bf16x8*>(Wt + (size_t)nc * 128 + ks * 32 + g8);
            }
            #pragma unroll
            for (int i = 0; i < 4; ++i)
                #pragma unroll
                for (int j = 0; j < 4; ++j)
                    acc[i][j] = __builtin_amdgcn_mfma_f32_16x16x32_bf16(af[i], bf[j], acc[i][j], 0, 0, 0);
        }
        #pragma unroll
        for (int i = 0; i < 4; ++i) {
            int gr0 = row0 + wm * 64 + i * 16 + ((lane >> 4) << 2);
            #pragma unroll
            for (int j = 0; j < 4; ++j) {
                int gc = cb * 128 + wn * 64 + j * 16 + (lane & 15);
                #pragma unroll
                for (int r = 0; r < 4; ++r)
                    out[(size_t)(gr0 + r) * 512 + gc] = f2bf(acc[i][j][r]);
            }
        }
    }
}

// ---------------- edge pass with in-kernel We2 projection ----------------
// Block = 64 edges, 256 threads, full 256 emb features.
// LDS ~44KB -> 3 blocks/CU (12 waves) for atomic/gather overlap.
__global__ __launch_bounds__(256) void edge_proj(
    const ushort* __restrict__ efb,   // [Ep,64] bf16 (zero-padded)
    const ushort* __restrict__ Wet,   // [256,64] bf16, n-major (We1_e^T)
    const ushort* __restrict__ We2t,  // [128,256] bf16, n-major (We2^T)
    const ushort* __restrict__ AB,    // [Np,512] bf16: row = [A(256) | B(256)]
    const int* __restrict__ src, const int* __restrict__ dst,
    ushort* __restrict__ H,           // [Np,128] bf16 accumulator
    int E)
{
    __shared__ ushort Cs[128 * YROW];      // 16896: C as [64][CSROW], Y as [128][YROW]
    __shared__ ushort efs[64 * LROW];      // ef tile
    __shared__ int sd[128];                // src[0..63] | dst[0..63]

    const int tid  = threadIdx.x;
    const int lane = tid & 63;
    const int wv   = tid >> 6;             // 0..3
    const int wm   = wv >> 1, wn = wv & 1;
    const int eb   = blockIdx.x * 64;
    const int g8   = (lane >> 4) * 8;

    // ---- stage ef tile (64x64 bf16) + edge endpoints ----
    #pragma unroll
    for (int q = 0; q < 2; ++q) {
        int idx = q * 256 + tid;           // 0..511
        int r = idx >> 3, c = (idx & 7) * 8;
        *reinterpret_cast<uint4*>(&efs[r * LROW + c]) =
            *reinterpret_cast<const uint4*>(efb + (size_t)(eb + r) * 64 + c);
    }
    if (tid < 64)       sd[tid] = (eb + tid < E) ? src[eb + tid] : -1;
    else if (tid < 128) sd[tid] = (eb + tid - 64 < E) ? dst[eb + tid - 64] : -1;
    __syncthreads();

    // ---- C = ef @ Wet : [64 x 256]; wave owns col quarter wv*64 ----
    f32x4 accc[4][4] = {};
    #pragma unroll
    for (int ks = 0; ks < 2; ++ks) {
        bf16x8 af[4], bf[4];
        #pragma unroll
        for (int i = 0; i < 4; ++i) {
            int er = i * 16 + (lane & 15);
            af[i] = *reinterpret_cast<const bf16x8*>(&efs[er * LROW + ks * 32 + g8]);
            int nc = wv * 64 + i * 16 + (lane & 15);
            bf[i] = *reinterpret_cast<const bf16x8*>(Wet + (size_t)nc * 64 + ks * 32 + g8);
        }
        #pragma unroll
        for (int i = 0; i < 4; ++i)
            #pragma unroll
            for (int j = 0; j < 4; ++j)
                accc[i][j] = __builtin_amdgcn_mfma_f32_16x16x32_bf16(af[i], bf[j], accc[i][j], 0, 0, 0);
    }
    // C/D layout: col = lane&15, row = (lane>>4)*4 + reg
    #pragma unroll
    for (int i = 0; i < 4; ++i) {
        int er0 = i * 16 + ((lane >> 4) << 2);
        #pragma unroll
        for (int j = 0; j < 4; ++j) {
            int fc = wv * 64 + j * 16 + (lane & 15);
            #pragma unroll
            for (int r = 0; r < 4; ++r)
                Cs[(er0 + r) * CSROW + fc] = f2bf(accc[i][j][r]);
        }
    }
    __syncthreads();

    // ---- Y[128 x 128] = lrelu(A[oth]+B[own]+C) @ We2t, K=256 ----
    // Y row r: r<64 = forward msg of edge r (-> H[dst]); r>=64 = backward
    // (-> H[src]). wm selects direction; msg A-frags built in registers.
    f32x4 acc[4][4] = {};
    #pragma unroll
    for (int ks = 0; ks < 8; ++ks) {
        bf16x8 mf[4], wf[4];
        #pragma unroll
        for (int i = 0; i < 4; ++i) {
            int el = i * 16 + (lane & 15);           // edge slot 0..63
            int a_ = wm ? sd[64 + el] : sd[el];      // "other" node
            int b_ = wm ? sd[el]      : sd[64 + el]; // "own" node
            if (a_ < 0) a_ = 0;                      // pad rows: garbage ok, skipped
            if (b_ < 0) b_ = 0;
            int k = ks * 32 + g8;
            bf16x8 a8 = *reinterpret_cast<const bf16x8*>(AB + (size_t)a_ * 512 + k);
            bf16x8 b8 = *reinterpret_cast<const bf16x8*>(AB + (size_t)b_ * 512 + 256 + k);
            bf16x8 c8 = *reinterpret_cast<const bf16x8*>(&Cs[el * CSROW + k]);
            bf16x8 m8;
            #pragma unroll
            for (int t = 0; t < 8; ++t) {
                float f = lrelu(bf2f((ushort)a8[t]) + bf2f((ushort)b8[t]) + bf2f((ushort)c8[t]));
                m8[t] = (short)f2bf(f);
            }
            mf[i] = m8;
        }
        #pragma unroll
        for (int j = 0; j < 4; ++j) {
            int nc = wn * 64 + j * 16 + (lane & 15);
            wf[j] = *reinterpret_cast<const bf16x8*>(We2t + (size_t)nc * 256 + ks * 32 + g8);
        }
        #pragma unroll
        for (int i = 0; i < 4; ++i)
            #pragma unroll
            for (int j = 0; j < 4; ++j)
                acc[i][j] = __builtin_amdgcn_mfma_f32_16x16x32_bf16(mf[i], wf[j], acc[i][j], 0, 0, 0);
    }
    __syncthreads();       // all Cs reads done -> alias as Ys

    ushort* Ys = Cs;
    #pragma unroll
    for (int i = 0; i < 4; ++i) {
        int yr0 = wm * 64 + i * 16 + ((lane >> 4) << 2);
        #pragma unroll
        for (int j = 0; j < 4; ++j) {
            int yc = wn * 64 + j * 16 + (lane & 15);
            #pragma unroll
            for (int r = 0; r < 4; ++r)
                Ys[(yr0 + r) * YROW + yc] = f2bf(acc[i][j][r]);
        }
    }
    __syncthreads();

    // ---- scatter: 1 pk-atomic per (row, lane); 256B contiguous per wave ----
    #pragma unroll
    for (int q = 0; q < 32; ++q) {
        int row = wv * 32 + q;
        int node = (row < 64) ? sd[64 + row] : sd[row - 64];
        if (node < 0) continue;                      // pad edge (wave-uniform)
        ushort2 yv = *(const ushort2*)(&Ys[row * YROW + lane * 2]);
        unsigned uv; memcpy(&uv, &yv, 4);
        atomic_pk_add_bf16(H + (size_t)node * 128 + lane * 2, uv);
    }
}

// ---------------- fused MLP tail: [nf|H] -> hid -> out ----------------
// H is already red (projection done edge-side). LDS overlays, 67.6KB.
__global__ __launch_bounds__(256) void mlp_fused(
    const ushort* __restrict__ H,     // [Np,128] bf16 (= red)
    const ushort* __restrict__ nfb,   // [Np,128] bf16
    const ushort* __restrict__ Wn1t,  // [256,256] bf16 n-major
    const ushort* __restrict__ Wn2t,  // [128,256] bf16 n-major
    float* __restrict__ out, int Nreal)
{
    __shared__ ushort lds[128 * P256];
    ushort* Ns  = lds;                  // [128][P128] nf tile
    ushort* Rs  = lds + 128 * P128;     // [128][P128] red tile
    ushort* Hid = lds;                  // overlay after phase A

    const int tid  = threadIdx.x;
    const int lane = tid & 63;
    const int wv   = tid >> 6;
    const int wm   = wv >> 1, wn = wv & 1;
    const int row0 = blockIdx.x * 128;
    const int g8   = (lane >> 4) * 8;

    #pragma unroll
    for (int q = 0; q < 8; ++q) {
        int idx = q * 256 + tid;
        int r = idx >> 4, c = (idx & 15) * 8;
        *reinterpret_cast<uint4*>(&Ns[r * P128 + c]) =
            *reinterpret_cast<const uint4*>(nfb + (size_t)(row0 + r) * 128 + c);
        *reinterpret_cast<uint4*>(&Rs[r * P128 + c]) =
            *reinterpret_cast<const uint4*>(H + (size_t)(row0 + r) * 128 + c);
    }
    __syncthreads();

    // ---- phase A: hid = lrelu([Ns | Rs] @ Wn1t), 256 out cols ----
    f32x4 a2[2][4][4] = {};
    #pragma unroll
    for (int cb = 0; cb < 2; ++cb) {
        #pragma unroll
        for (int ks = 0; ks < 8; ++ks) {
            bf16x8 af[4], bf[4];
            #pragma unroll
            for (int i = 0; i < 4; ++i) {
                int mrow = wm * 64 + i * 16 + (lane & 15);
                af[i] = (ks < 4)
                    ? *reinterpret_cast<const bf16x8*>(&Ns[mrow * P128 + ks * 32 + g8])
                    : *reinterpret_cast<const bf16x8*>(&Rs[mrow * P128 + (ks - 4) * 32 + g8]);
                int nc = cb * 128 + wn * 64 + i * 16 + (lane & 15);
                bf[i] = *reinterpret_cast<const bf16x8*>(Wn1t + (size_t)nc * 256 + ks * 32 + g8);
            }
            #pragma unroll
            for (int i = 0; i < 4; ++i)
                #pragma unroll
                for (int j = 0; j < 4; ++j)
                    a2[cb][i][j] = __builtin_amdgcn_mfma_f32_16x16x32_bf16(af[i], bf[j], a2[cb][i][j], 0, 0, 0);
        }
    }
    __syncthreads();   // Ns/Rs reads done -> overlay Hid

    #pragma unroll
    for (int cb = 0; cb < 2; ++cb)
        #pragma unroll
        for (int i = 0; i < 4; ++i) {
            int er0 = wm * 64 + i * 16 + ((lane >> 4) << 2);
            #pragma unroll
            for (int j = 0; j < 4; ++j) {
                int fc = cb * 128 + wn * 64 + j * 16 + (lane & 15);
                #pragma unroll
                for (int r = 0; r < 4; ++r)
                    Hid[(er0 + r) * P256 + fc] = f2bf(lrelu(a2[cb][i][j][r]));
            }
        }
    __syncthreads();

    // ---- phase B: out = Hid @ Wn2t (fp32, guarded) ----
    f32x4 a3[4][4] = {};
    #pragma unroll
    for (int ks = 0; ks < 8; ++ks) {
        bf16x8 af[4], bf[4];
        #pragma unroll
        for (int i = 0; i < 4; ++i) {
            int mrow = wm * 64 + i * 16 + (lane & 15);
            af[i] = *reinterpret_cast<const bf16x8*>(&Hid[mrow * P256 + ks * 32 + g8]);
            int nc = wn * 64 + i * 16 + (lane & 15);
            bf[i] = *reinterpret_cast<const bf16x8*>(Wn2t + (size_t)nc * 256 + ks * 32 + g8);
        }
        #pragma unroll
        for (int i = 0; i < 4; ++i)
            #pragma unroll
            for (int j = 0; j < 4; ++j)
                a3[i][j] = __builtin_amdgcn_mfma_f32_16x16x32_bf16(af[i], bf[j], a3[i][j], 0, 0, 0);
    }
    #pragma unroll
    for (int i = 0; i < 4; ++i) {
        int gr0 = row0 + wm * 64 + i * 16 + ((lane >> 4) << 2);
        #pragma unroll
        for (int j = 0; j < 4; ++j) {
            int gc = wn * 64 + j * 16 + (lane & 15);
            #pragma unroll
            for (int r = 0; r < 4; ++r) {
                int gr = gr0 + r;
                if (gr < Nreal) out[(size_t)gr * 128 + gc] = a3[i][j][r];
            }
        }
    }
}

// float -> bf16 with zero padding; n_real, n_pad multiples of 4
__global__ __launch_bounds__(256) void cvt_pad(
    const float* __restrict__ x, ushort* __restrict__ y, size_t n_real, size_t n_pad)
{
    size_t i = ((size_t)blockIdx.x * 256 + threadIdx.x) * 4;
    if (i >= n_pad) return;
    ushort4 o;
    if (i < n_real) {
        float4 v = *(const float4*)(x + i);
        o.x = f2bf(v.x); o.y = f2bf(v.y); o.z = f2bf(v.z); o.w = f2bf(v.w);
    } else { o.x = 0; o.y = 0; o.z = 0; o.w = 0; }
    *(ushort4*)(y + i) = o;
}

// transpose + convert all weights to bf16 [N,K] layouts
__global__ __launch_bounds__(256) void wcvt(
    const float* __restrict__ We1, const float* __restrict__ We2,
    const float* __restrict__ Wn1, const float* __restrict__ Wn2,
    ushort* __restrict__ Wabt, ushort* __restrict__ Wet, ushort* __restrict__ We2t,
    ushort* __restrict__ Wn1t, ushort* __restrict__ Wn2t)
{
    int idx = blockIdx.x * 256 + threadIdx.x;
    switch (blockIdx.y) {
    case 0: if (idx < 256*128) { int n = idx >> 7, k = idx & 127; Wabt[idx]            = f2bf(We1[k * 256 + n]); } break;
    case 1: if (idx < 256*128) { int n = idx >> 7, k = idx & 127; Wabt[32768 + idx]    = f2bf(We1[(128 + k) * 256 + n]); } break;
    case 2: if (idx < 256*64)  { int n = idx >> 6, k = idx & 63;  Wet[idx]             = f2bf(We1[(256 + k) * 256 + n]); } break;
    case 3: if (idx < 128*256) { int n = idx >> 8, k = idx & 255; We2t[idx]            = f2bf(We2[k * 128 + n]); } break;
    case 4: if (idx < 256*256) { int n = idx >> 8, k = idx & 255; Wn1t[idx]            = f2bf(Wn1[k * 256 + n]); } break;
    case 5: if (idx < 128*256) { int n = idx >> 8, k = idx & 255; Wn2t[idx]            = f2bf(Wn2[k * 128 + n]); } break;
    }
}

extern "C" void kernel_launch(void* const* d_in, const int* in_sizes, int n_in,
                              void* d_out, int out_size, void* d_ws, size_t ws_size,
                              hipStream_t stream) {
    const float* nf  = (const float*)d_in[0];
    const float* ef  = (const float*)d_in[1];
    const int*   src = (const int*)d_in[2];
    const int*   dst = (const int*)d_in[3];
    const float* We1 = (const float*)d_in[4];
    const float* We2 = (const float*)d_in[5];
    const float* Wn1 = (const float*)d_in[6];
    const float* Wn2 = (const float*)d_in[7];
    float* out = (float*)d_out;

    const int  N  = in_sizes[0] / 128;            // 100000
    const int  E  = in_sizes[2];                  // 500000
    const int  Np = (N + 127) & ~127;             // 100096
    const long Ep = ((long)E + 127) & ~127L;      // 500096

    char* p = (char*)d_ws;
    auto alloc = [&](size_t bytes) { char* r = p; p += (bytes + 255) & ~(size_t)255; return r; };
    ushort* AB   = (ushort*)alloc((size_t)Np * 512 * 2);
    ushort* H    = (ushort*)alloc((size_t)Np * 128 * 2);   // [Np,128] bf16 (= red)
    ushort* nfb  = (ushort*)alloc((size_t)Np * 128 * 2);
    ushort* efb  = (ushort*)alloc((size_t)Ep * 64 * 2);
    ushort* Wabt = (ushort*)alloc(65536 * 2);
    ushort* Wet  = (ushort*)alloc(16384 * 2);
    ushort* We2t = (ushort*)alloc(32768 * 2);
    ushort* Wn1t = (ushort*)alloc(65536 * 2);
    ushort* Wn2t = (ushort*)alloc(32768 * 2);

    dim3 blk(256);

    wcvt<<<dim3(256, 6), blk, 0, stream>>>(We1, We2, Wn1, Wn2, Wabt, Wet, We2t, Wn1t, Wn2t);
    cvt_pad<<<dim3((unsigned)((size_t)Np * 128 / 1024)), blk, 0, stream>>>(nf, nfb, (size_t)N * 128, (size_t)Np * 128);
    cvt_pad<<<dim3((unsigned)((size_t)Ep * 64 / 1024)), blk, 0, stream>>>(ef, efb, (size_t)E * 64, (size_t)Ep * 64);

    // AB = nf @ [We1_s | We1_d]
    gemm_ab<<<dim3(Np / 128), blk, 0, stream>>>(nfb, Wabt, AB);

    hipMemsetAsync(H, 0, (size_t)Np * 128 * 2, stream);

    // edge pass with in-kernel We2 projection (64M pk-atomics, was 128M)
    edge_proj<<<dim3((unsigned)(Ep / 64)), blk, 0, stream>>>(
        efb, Wet, We2t, AB, src, dst, H, E);

    // hid = lrelu([nf|H] @ Wn1); out = hid @ Wn2
    mlp_fused<<<dim3(Np / 128), blk, 0, stream>>>(H, nfb, Wn1t, Wn2t, out, N);
}

// Round 5
// 771.483 us; speedup vs baseline: 1.1847x; 1.1847x over previous
//
#include <hip/hip_runtime.h>
#include <hip/hip_bf16.h>
#include <string.h>

// GNN layer, round 5: round-4 algebra (We2 projection edge-side -> 64M
// atomics) + round-1 access patterns (row-contiguous gathers, LDS transpose
// to fragment layout).
//   AB = nf @ [We1_s|We1_d]                      (gemm_ab)
//   edge_msg (per 32-edge block):
//     C  = ef_tile @ We1_e   (MFMA, K=64, ef frags from contiguous global)
//     Ms = lrelu(A[oth]+B[own]+C)  built wave-per-row, lane-per-feature-pair
//          (every gather instruction = 256B contiguous) -> LDS [64][256]
//     Y  = Ms @ We2t         (MFMA, K=256, frags from LDS)
//     H[own] += Y            (pk_add_bf16, 256B-contiguous per wave)
//   mlp:  hid = lrelu([nf|H]@Wn1) ; out = hid @ Wn2
// Round-4 lesson encoded: NEVER feed MFMA fragments from random gathers --
// gather row-contiguous, transpose through LDS.

using f32x4  = __attribute__((ext_vector_type(4))) float;
using bf16x8 = __attribute__((ext_vector_type(8))) short;

#define P128 132   // K=128 LDS tile pitch (264 B)
#define P256 264   // K=256 LDS tile pitch (528 B)
#define YROW 132   // Ys pitch: 64 rows x 128 cols

__device__ __forceinline__ float lrelu(float x) { return x >= 0.f ? x : 0.01f * x; }

__device__ __forceinline__ ushort f2bf(float f) {
    union { float f; unsigned u; } v; v.f = f;
    unsigned u = v.u;
    return (ushort)((u + 0x7fffu + ((u >> 16) & 1u)) >> 16);   // RNE
}
__device__ __forceinline__ float bf2f(ushort u) {
    union { unsigned u; float f; } v; v.u = ((unsigned)u) << 16; return v.f;
}

__device__ __forceinline__ void atomic_pk_add_bf16(void* addr, unsigned val) {
    asm volatile("global_atomic_pk_add_bf16 %0, %1, off" : : "v"(addr), "v"(val) : "memory");
}

// ---------------- AB GEMM: X staged once, W frags from global ----------------
__global__ __launch_bounds__(256) void gemm_ab(
    const ushort* __restrict__ X,     // [Np,128] bf16
    const ushort* __restrict__ Wt,    // [512,128] bf16
    ushort* __restrict__ out)         // [Np,512] bf16
{
    __shared__ ushort Xs[128 * P128];
    const int tid  = threadIdx.x;
    const int lane = tid & 63;
    const int wv   = tid >> 6;
    const int wm   = wv >> 1, wn = wv & 1;
    const int row0 = blockIdx.x * 128;

    #pragma unroll
    for (int q = 0; q < 8; ++q) {
        int idx = q * 256 + tid;
        int r = idx >> 4, c = idx & 15;
        *reinterpret_cast<uint4*>(&Xs[r * P128 + c * 8]) =
            *reinterpret_cast<const uint4*>(X + (size_t)(row0 + r) * 128 + c * 8);
    }
    __syncthreads();

    const int g8 = (lane >> 4) * 8;
    for (int cb = 0; cb < 4; ++cb) {
        f32x4 acc[4][4] = {};
        #pragma unroll
        for (int ks = 0; ks < 4; ++ks) {
            bf16x8 af[4], bf[4];
            #pragma unroll
            for (int i = 0; i < 4; ++i) {
                int mrow = wm * 64 + i * 16 + (lane & 15);
                af[i] = *reinterpret_cast<const bf16x8*>(&Xs[mrow * P128 + ks * 32 + g8]);
                int nc = cb * 128 + wn * 64 + i * 16 + (lane & 15);
                bf[i] = *reinterpret_cast<const bf16x8*>(Wt + (size_t)nc * 128 + ks * 32 + g8);
            }
            #pragma unroll
            for (int i = 0; i < 4; ++i)
                #pragma unroll
                for (int j = 0; j < 4; ++j)
                    acc[i][j] = __builtin_amdgcn_mfma_f32_16x16x32_bf16(af[i], bf[j], acc[i][j], 0, 0, 0);
        }
        #pragma unroll
        for (int i = 0; i < 4; ++i) {
            int gr0 = row0 + wm * 64 + i * 16 + ((lane >> 4) << 2);
            #pragma unroll
            for (int j = 0; j < 4; ++j) {
                int gc = cb * 128 + wn * 64 + j * 16 + (lane & 15);
                #pragma unroll
                for (int r = 0; r < 4; ++r)
                    out[(size_t)(gr0 + r) * 512 + gc] = f2bf(acc[i][j][r]);
            }
        }
    }
}

// ---------------- edge pass: msg-tile in LDS, projected scatter ----------------
// Block = 32 edges, 256 threads. LDS 51.2KB -> 3 blocks/CU.
// Msg rows: m in [0,32) = forward (own=dst, oth=src); m in [32,64) = backward.
__global__ __launch_bounds__(256) void edge_msg(
    const ushort* __restrict__ efb,   // [Ep,64] bf16 (zero-padded)
    const ushort* __restrict__ Wet,   // [256,64] bf16, n-major (We1_e^T)
    const ushort* __restrict__ We2t,  // [128,256] bf16, n-major (We2^T)
    const ushort* __restrict__ AB,    // [Np,512] bf16: row = [A(256) | B(256)]
    const int* __restrict__ src, const int* __restrict__ dst,
    ushort* __restrict__ H,           // [Np,128] bf16 accumulator
    int E)
{
    __shared__ ushort Ms[64 * P256];       // 33.8KB msg tile
    __shared__ ushort Cs[32 * P256];       // 16.9KB C tile; aliased as Ys[64][YROW]
    __shared__ int own_s[64], oth_s[64];

    const int tid  = threadIdx.x;
    const int lane = tid & 63;
    const int wv   = tid >> 6;             // 0..3
    const int eb   = blockIdx.x * 32;
    const int g8   = (lane >> 4) * 8;

    if (tid < 32) {
        int e = eb + tid;
        int s_ = (e < E) ? src[e] : -1;
        int d_ = (e < E) ? dst[e] : -1;
        own_s[tid]      = d_;                    // forward: into dst
        oth_s[tid]      = (s_ < 0) ? 0 : s_;
        own_s[32 + tid] = s_;                    // backward: into src
        oth_s[32 + tid] = (d_ < 0) ? 0 : d_;
    }

    // ---- C = ef[eb..eb+31] @ Wet : [32 x 256]; wave owns cols wv*64..+63 ----
    // ef frags read straight from global: block's ef tile = contiguous 4KB.
    f32x4 ac[2][4] = {};
    #pragma unroll
    for (int ks = 0; ks < 2; ++ks) {
        bf16x8 af[2], bf[4];
        #pragma unroll
        for (int i = 0; i < 2; ++i) {
            int er = i * 16 + (lane & 15);
            af[i] = *reinterpret_cast<const bf16x8*>(efb + (size_t)(eb + er) * 64 + ks * 32 + g8);
        }
        #pragma unroll
        for (int j = 0; j < 4; ++j) {
            int nc = wv * 64 + j * 16 + (lane & 15);
            bf[j] = *reinterpret_cast<const bf16x8*>(Wet + (size_t)nc * 64 + ks * 32 + g8);
        }
        #pragma unroll
        for (int i = 0; i < 2; ++i)
            #pragma unroll
            for (int j = 0; j < 4; ++j)
                ac[i][j] = __builtin_amdgcn_mfma_f32_16x16x32_bf16(af[i], bf[j], ac[i][j], 0, 0, 0);
    }
    // C/D layout: col = lane&15, row = (lane>>4)*4 + reg
    #pragma unroll
    for (int i = 0; i < 2; ++i) {
        int er0 = i * 16 + ((lane >> 4) << 2);
        #pragma unroll
        for (int j = 0; j < 4; ++j) {
            int fc = wv * 64 + j * 16 + (lane & 15);
            #pragma unroll
            for (int r = 0; r < 4; ++r)
                Cs[(er0 + r) * P256 + fc] = f2bf(ac[i][j][r]);
        }
    }
    __syncthreads();   // Cs + own_s/oth_s visible

    // ---- msg build: wave = msg row, lane = feature pair (256B contiguous) ----
    #pragma unroll 4
    for (int p = 0; p < 16; ++p) {
        int m   = p * 4 + wv;
        int oth = oth_s[m];
        int own = own_s[m];
        int ownc = (own < 0) ? 0 : own;
        int rc  = m & 31;                  // C row = edge slot
        #pragma unroll
        for (int h = 0; h < 2; ++h) {
            int c = h * 128 + lane * 2;
            ushort2 av = *(const ushort2*)(AB + (size_t)oth  * 512 + c);
            ushort2 bv = *(const ushort2*)(AB + (size_t)ownc * 512 + 256 + c);
            ushort2 cv = *(const ushort2*)(&Cs[rc * P256 + c]);
            ushort2 mv;
            mv.x = f2bf(lrelu(bf2f(av.x) + bf2f(bv.x) + bf2f(cv.x)));
            mv.y = f2bf(lrelu(bf2f(av.y) + bf2f(bv.y) + bf2f(cv.y)));
            *(ushort2*)(&Ms[m * P256 + c]) = mv;
        }
    }
    __syncthreads();   // Ms ready; Cs reads done -> safe to alias as Ys

    // ---- Y = Ms @ We2t : [64 x 128], K=256 ----
    const int wm = wv >> 1, wn = wv & 1;
    f32x4 ay[2][4] = {};
    #pragma unroll
    for (int ks = 0; ks < 8; ++ks) {
        bf16x8 af[2], bf[4];
        #pragma unroll
        for (int i = 0; i < 2; ++i) {
            int mrow = wm * 32 + i * 16 + (lane & 15);
            af[i] = *reinterpret_cast<const bf16x8*>(&Ms[mrow * P256 + ks * 32 + g8]);
        }
        #pragma unroll
        for (int j = 0; j < 4; ++j) {
            int nc = wn * 64 + j * 16 + (lane & 15);
            bf[j] = *reinterpret_cast<const bf16x8*>(We2t + (size_t)nc * 256 + ks * 32 + g8);
        }
        #pragma unroll
        for (int i = 0; i < 2; ++i)
            #pragma unroll
            for (int j = 0; j < 4; ++j)
                ay[i][j] = __builtin_amdgcn_mfma_f32_16x16x32_bf16(af[i], bf[j], ay[i][j], 0, 0, 0);
    }
    ushort* Ys = Cs;   // alias (16896 ushorts each)
    #pragma unroll
    for (int i = 0; i < 2; ++i) {
        int yr0 = wm * 32 + i * 16 + ((lane >> 4) << 2);
        #pragma unroll
        for (int j = 0; j < 4; ++j) {
            int yc = wn * 64 + j * 16 + (lane & 15);
            #pragma unroll
            for (int r = 0; r < 4; ++r)
                Ys[(yr0 + r) * YROW + yc] = f2bf(ay[i][j][r]);
        }
    }
    __syncthreads();

    // ---- scatter: 1 pk-atomic per (row, lane); 256B contiguous per wave ----
    #pragma unroll 4
    for (int q = 0; q < 16; ++q) {
        int row  = wv * 16 + q;
        int node = own_s[row];
        if (node < 0) continue;            // pad edge (wave-uniform)
        ushort2 yv = *(const ushort2*)(&Ys[row * YROW + lane * 2]);
        unsigned uv; memcpy(&uv, &yv, 4);
        atomic_pk_add_bf16(H + (size_t)node * 128 + lane * 2, uv);
    }
}

// ---------------- fused MLP tail: [nf|H] -> hid -> out ----------------
__global__ __launch_bounds__(256) void mlp_fused(
    const ushort* __restrict__ H,     // [Np,128] bf16 (= red)
    const ushort* __restrict__ nfb,   // [Np,128] bf16
    const ushort* __restrict__ Wn1t,  // [256,256] bf16 n-major
    const ushort* __restrict__ Wn2t,  // [128,256] bf16 n-major
    float* __restrict__ out, int Nreal)
{
    __shared__ ushort lds[128 * P256];
    ushort* Ns  = lds;                  // [128][P128] nf tile
    ushort* Rs  = lds + 128 * P128;     // [128][P128] red tile
    ushort* Hid = lds;                  // overlay after phase A

    const int tid  = threadIdx.x;
    const int lane = tid & 63;
    const int wv   = tid >> 6;
    const int wm   = wv >> 1, wn = wv & 1;
    const int row0 = blockIdx.x * 128;
    const int g8   = (lane >> 4) * 8;

    #pragma unroll
    for (int q = 0; q < 8; ++q) {
        int idx = q * 256 + tid;
        int r = idx >> 4, c = (idx & 15) * 8;
        *reinterpret_cast<uint4*>(&Ns[r * P128 + c]) =
            *reinterpret_cast<const uint4*>(nfb + (size_t)(row0 + r) * 128 + c);
        *reinterpret_cast<uint4*>(&Rs[r * P128 + c]) =
            *reinterpret_cast<const uint4*>(H + (size_t)(row0 + r) * 128 + c);
    }
    __syncthreads();

    // ---- phase A: hid = lrelu([Ns | Rs] @ Wn1t), 256 out cols ----
    f32x4 a2[2][4][4] = {};
    #pragma unroll
    for (int cb = 0; cb < 2; ++cb) {
        #pragma unroll
        for (int ks = 0; ks < 8; ++ks) {
            bf16x8 af[4], bf[4];
            #pragma unroll
            for (int i = 0; i < 4; ++i) {
                int mrow = wm * 64 + i * 16 + (lane & 15);
                af[i] = (ks < 4)
                    ? *reinterpret_cast<const bf16x8*>(&Ns[mrow * P128 + ks * 32 + g8])
                    : *reinterpret_cast<const bf16x8*>(&Rs[mrow * P128 + (ks - 4) * 32 + g8]);
                int nc = cb * 128 + wn * 64 + i * 16 + (lane & 15);
                bf[i] = *reinterpret_cast<const bf16x8*>(Wn1t + (size_t)nc * 256 + ks * 32 + g8);
            }
            #pragma unroll
            for (int i = 0; i < 4; ++i)
                #pragma unroll
                for (int j = 0; j < 4; ++j)
                    a2[cb][i][j] = __builtin_amdgcn_mfma_f32_16x16x32_bf16(af[i], bf[j], a2[cb][i][j], 0, 0, 0);
        }
    }
    __syncthreads();   // Ns/Rs reads done -> overlay Hid

    #pragma unroll
    for (int cb = 0; cb < 2; ++cb)
        #pragma unroll
        for (int i = 0; i < 4; ++i) {
            int er0 = wm * 64 + i * 16 + ((lane >> 4) << 2);
            #pragma unroll
            for (int j = 0; j < 4; ++j) {
                int fc = cb * 128 + wn * 64 + j * 16 + (lane & 15);
                #pragma unroll
                for (int r = 0; r < 4; ++r)
                    Hid[(er0 + r) * P256 + fc] = f2bf(lrelu(a2[cb][i][j][r]));
            }
        }
    __syncthreads();

    // ---- phase B: out = Hid @ Wn2t (fp32, guarded) ----
    f32x4 a3[4][4] = {};
    #pragma unroll
    for (int ks = 0; ks < 8; ++ks) {
        bf16x8 af[4], bf[4];
        #pragma unroll
        for (int i = 0; i < 4; ++i) {
            int mrow = wm * 64 + i * 16 + (lane & 15);
            af[i] = *reinterpret_cast<const bf16x8*>(&Hid[mrow * P256 + ks * 32 + g8]);
            int nc = wn * 64 + i * 16 + (lane & 15);
            bf[i] = *reinterpret_cast<const bf16x8*>(Wn2t + (size_t)nc * 256 + ks * 32 + g8);
        }
        #pragma unroll
        for (int i = 0; i < 4; ++i)
            #pragma unroll
            for (int j = 0; j < 4; ++j)
                a3[i][j] = __builtin_amdgcn_mfma_f32_16x16x32_bf16(af[i], bf[j], a3[i][j], 0, 0, 0);
    }
    #pragma unroll
    for (int i = 0; i < 4; ++i) {
        int gr0 = row0 + wm * 64 + i * 16 + ((lane >> 4) << 2);
        #pragma unroll
        for (int j = 0; j < 4; ++j) {
            int gc = wn * 64 + j * 16 + (lane & 15);
            #pragma unroll
            for (int r = 0; r < 4; ++r) {
                int gr = gr0 + r;
                if (gr < Nreal) out[(size_t)gr * 128 + gc] = a3[i][j][r];
            }
        }
    }
}

// float -> bf16 with zero padding; n_real, n_pad multiples of 4
__global__ __launch_bounds__(256) void cvt_pad(
    const float* __restrict__ x, ushort* __restrict__ y, size_t n_real, size_t n_pad)
{
    size_t i = ((size_t)blockIdx.x * 256 + threadIdx.x) * 4;
    if (i >= n_pad) return;
    ushort4 o;
    if (i < n_real) {
        float4 v = *(const float4*)(x + i);
        o.x = f2bf(v.x); o.y = f2bf(v.y); o.z = f2bf(v.z); o.w = f2bf(v.w);
    } else { o.x = 0; o.y = 0; o.z = 0; o.w = 0; }
    *(ushort4*)(y + i) = o;
}

// transpose + convert all weights to bf16 [N,K] layouts
__global__ __launch_bounds__(256) void wcvt(
    const float* __restrict__ We1, const float* __restrict__ We2,
    const float* __restrict__ Wn1, const float* __restrict__ Wn2,
    ushort* __restrict__ Wabt, ushort* __restrict__ Wet, ushort* __restrict__ We2t,
    ushort* __restrict__ Wn1t, ushort* __restrict__ Wn2t)
{
    int idx = blockIdx.x * 256 + threadIdx.x;
    switch (blockIdx.y) {
    case 0: if (idx < 256*128) { int n = idx >> 7, k = idx & 127; Wabt[idx]            = f2bf(We1[k * 256 + n]); } break;
    case 1: if (idx < 256*128) { int n = idx >> 7, k = idx & 127; Wabt[32768 + idx]    = f2bf(We1[(128 + k) * 256 + n]); } break;
    case 2: if (idx < 256*64)  { int n = idx >> 6, k = idx & 63;  Wet[idx]             = f2bf(We1[(256 + k) * 256 + n]); } break;
    case 3: if (idx < 128*256) { int n = idx >> 8, k = idx & 255; We2t[idx]            = f2bf(We2[k * 128 + n]); } break;
    case 4: if (idx < 256*256) { int n = idx >> 8, k = idx & 255; Wn1t[idx]            = f2bf(Wn1[k * 256 + n]); } break;
    case 5: if (idx < 128*256) { int n = idx >> 8, k = idx & 255; Wn2t[idx]            = f2bf(Wn2[k * 128 + n]); } break;
    }
}

extern "C" void kernel_launch(void* const* d_in, const int* in_sizes, int n_in,
                              void* d_out, int out_size, void* d_ws, size_t ws_size,
                              hipStream_t stream) {
    const float* nf  = (const float*)d_in[0];
    const float* ef  = (const float*)d_in[1];
    const int*   src = (const int*)d_in[2];
    const int*   dst = (const int*)d_in[3];
    const float* We1 = (const float*)d_in[4];
    const float* We2 = (const float*)d_in[5];
    const float* Wn1 = (const float*)d_in[6];
    const float* Wn2 = (const float*)d_in[7];
    float* out = (float*)d_out;

    const int  N  = in_sizes[0] / 128;            // 100000
    const int  E  = in_sizes[2];                  // 500000
    const int  Np = (N + 127) & ~127;             // 100096
    const long Ep = ((long)E + 127) & ~127L;      // 500096

    char* p = (char*)d_ws;
    auto alloc = [&](size_t bytes) { char* r = p; p += (bytes + 255) & ~(size_t)255; return r; };
    ushort* AB   = (ushort*)alloc((size_t)Np * 512 * 2);
    ushort* H    = (ushort*)alloc((size_t)Np * 128 * 2);   // [Np,128] bf16 (= red)
    ushort* nfb  = (ushort*)alloc((size_t)Np * 128 * 2);
    ushort* efb  = (ushort*)alloc((size_t)Ep * 64 * 2);
    ushort* Wabt = (ushort*)alloc(65536 * 2);
    ushort* Wet  = (ushort*)alloc(16384 * 2);
    ushort* We2t = (ushort*)alloc(32768 * 2);
    ushort* Wn1t = (ushort*)alloc(65536 * 2);
    ushort* Wn2t = (ushort*)alloc(32768 * 2);

    dim3 blk(256);

    wcvt<<<dim3(256, 6), blk, 0, stream>>>(We1, We2, Wn1, Wn2, Wabt, Wet, We2t, Wn1t, Wn2t);
    cvt_pad<<<dim3((unsigned)((size_t)Np * 128 / 1024)), blk, 0, stream>>>(nf, nfb, (size_t)N * 128, (size_t)Np * 128);
    cvt_pad<<<dim3((unsigned)((size_t)Ep * 64 / 1024)), blk, 0, stream>>>(ef, efb, (size_t)E * 64, (size_t)Ep * 64);

    // AB = nf @ [We1_s | We1_d]
    gemm_ab<<<dim3(Np / 128), blk, 0, stream>>>(nfb, Wabt, AB);

    hipMemsetAsync(H, 0, (size_t)Np * 128 * 2, stream);

    // edge pass: msg tile through LDS, projected scatter (64M pk-atomics)
    edge_msg<<<dim3((unsigned)(Ep / 32)), blk, 0, stream>>>(
        efb, Wet, We2t, AB, src, dst, H, E);

    // hid = lrelu([nf|H] @ Wn1); out = hid @ Wn2
    mlp_fused<<<dim3(Np / 128), blk, 0, stream>>>(H, nfb, Wn1t, Wn2t, out, N);
}